// Round 1
// baseline (661.100 us; speedup 1.0000x reference)
//
#include <hip/hip_runtime.h>

// SMFNet: V = relu(X @ Wg.T), F = relu(X @ Wf.T), out[i] = F[i,0]*V[i] + F[i,1]*V[(i+1)%N]
// X: [N,128] f32, Wf/Wg: [2,128] f32, out: [N,2] f32.
// Memory-bound: 512 MB X read dominates. Single pass; each block computes V for
// one extra row so the roll(-1) never crosses a block boundary (no workspace).

constexpr int ROWS  = 64;   // rows owned per block
constexpr int BLOCK = 256;  // 4 waves; each 32-lane half-wave handles one row/iter

__global__ __launch_bounds__(BLOCK) void smfnet_kernel(
    const float* __restrict__ X,
    const float* __restrict__ Wf,
    const float* __restrict__ Wg,
    float* __restrict__ out,
    int N)
{
    __shared__ float4 lds[ROWS + 1];  // per virtual row: (v0, v1, f0, f1)

    const int tid  = threadIdx.x;
    const int wave = tid >> 6;        // 0..3
    const int lane = tid & 63;
    const int half = lane >> 5;       // 0 or 1
    const int sub  = lane & 31;       // column group 0..31

    const int r0  = blockIdx.x * ROWS;
    const int num = min(ROWS, N - r0);   // rows this block owns

    // Per-lane weight fragments: columns [sub*4, sub*4+3]. Cached in L1/L2.
    const float4 wg0 = ((const float4*)(Wg      ))[sub];
    const float4 wg1 = ((const float4*)(Wg + 128))[sub];
    const float4 wf0 = ((const float4*)(Wf      ))[sub];
    const float4 wf1 = ((const float4*)(Wf + 128))[sub];

    // Virtual rows 0..num inclusive; vr==num is the "next block's first row"
    // (wraps to row 0 for the last block), for which only V is consumed.
    // 8 rows per iteration (4 waves x 2 half-waves).
    #pragma unroll
    for (int t = 0; t < (ROWS / 8) + 1; ++t) {
        const int vr = t * 8 + wave * 2 + half;
        if (vr <= num) {
            int i = r0 + vr;
            if (i >= N) i -= N;                       // wraparound for roll(-1)
            const float4 x = ((const float4*)(X + (size_t)i * 128))[sub];

            float g0 = x.x*wg0.x + x.y*wg0.y + x.z*wg0.z + x.w*wg0.w;
            float g1 = x.x*wg1.x + x.y*wg1.y + x.z*wg1.z + x.w*wg1.w;
            float f0 = x.x*wf0.x + x.y*wf0.y + x.z*wf0.z + x.w*wf0.w;
            float f1 = x.x*wf1.x + x.y*wf1.y + x.z*wf1.z + x.w*wf1.w;

            // Butterfly reduce across the 32-lane half (xor masks 1..16 stay
            // within the half; all 32 lanes share the same predicate).
            #pragma unroll
            for (int m = 1; m <= 16; m <<= 1) {
                g0 += __shfl_xor(g0, m);
                g1 += __shfl_xor(g1, m);
                f0 += __shfl_xor(f0, m);
                f1 += __shfl_xor(f1, m);
            }

            if (sub == 0) {
                lds[vr] = make_float4(fmaxf(g0, 0.f), fmaxf(g1, 0.f),
                                      fmaxf(f0, 0.f), fmaxf(f1, 0.f));
            }
        }
    }
    __syncthreads();

    // Epilogue: out[i] = F[i,0]*V[i] + F[i,1]*V[i+1]; coalesced float2 stores.
    if (tid < num) {
        const float4 cur = lds[tid];
        const float4 nxt = lds[tid + 1];
        const float o0 = cur.z * cur.x + cur.w * nxt.x;
        const float o1 = cur.z * cur.y + cur.w * nxt.y;
        ((float2*)out)[(size_t)(r0 + tid)] = make_float2(o0, o1);
    }
}

extern "C" void kernel_launch(void* const* d_in, const int* in_sizes, int n_in,
                              void* d_out, int out_size, void* d_ws, size_t ws_size,
                              hipStream_t stream) {
    const float* X  = (const float*)d_in[0];
    const float* Wf = (const float*)d_in[1];
    const float* Wg = (const float*)d_in[2];
    float* out = (float*)d_out;

    const int N = in_sizes[0] / 128;
    const int grid = (N + ROWS - 1) / ROWS;
    smfnet_kernel<<<grid, BLOCK, 0, stream>>>(X, Wf, Wg, out, N);
}